// Round 4
// baseline (271.631 us; speedup 1.0000x reference)
//
#include <hip/hip_runtime.h>

// SAR-ADC 4-bit successive-approximation quantizer.
// Element-wise over N = LENGTH*NADC = 12M floats. Memory-bound:
//   read x (48 MB), write q (48 MB) + Q (192 MB); roofline ~46 us @6.3 TB/s.
//
// v4: every global access is 16 B/lane lane-contiguous dwordx4.
//   - thread owns 4 consecutive elements: float4 x load, float4 q store.
//   - Q (4 float4/thread, would be 64 B lane stride) is staged through LDS
//     with an XOR swizzle (slot ^ ((slot>>4)&3)): writes are 2-way (free,
//     m136), reads conflict-free; then stored lane-contiguous in 4 passes.
//   - no nontemporal hints (v2: NT + strided stores -> 2x write amplify).
//
// Numerics: reference does float32 ops throughout. (Q+1)*0.5 is exactly
// 0.0 or 1.0, so each bit_sum = fl(W[m]*VREF) + subset of fl(W[k]*VR),
// added in the reference's fixed order. __fmul_rn/__fadd_rn prevent FMA
// contraction -> bit-exact thresholds -> bit-exact sign decisions.
// sign(x - b + 1e-30) == (x >= b ? +1 : -1): nonzero diffs are >= ~1e-9,
// DELTA only rescues diff==0.  (absmax has measured 0.0 since round 1.)

__global__ __launch_bounds__(256)
void sar_adc_kernel(const float4* __restrict__ x4, const float* __restrict__ W,
                    float4* __restrict__ q4, float4* __restrict__ Q4, int n)
{
    __shared__ float4 lds[1024];           // 16 KB: one float4 per element of block tile

    const int tid = threadIdx.x;
    const int e0  = blockIdx.x * 1024;     // first element of this block's tile
    const int t4  = blockIdx.x * 256 + tid;   // this thread's float4 index (x, q)

    const float VREF = 0.1125f;            // fl32(1.8/16)
    const float VR   = 0.1125f;

    // Wave-uniform W loads (compiler lifts to s_load).
    float w0 = W[0], w1 = W[1], w2 = W[2], w3 = W[3], w4 = W[4];
    float w5 = W[5], w6 = W[6], w7 = W[7], w8 = W[8], w9 = W[9];

    // fl(W[k]*VR) terms (exactly the reference's contribution when bit set)
    float wv0 = __fmul_rn(w0, VR);
    float wv1 = __fmul_rn(w1, VR);
    float wv2 = __fmul_rn(w2, VR);
    float wv4 = __fmul_rn(w4, VR);
    float wv5 = __fmul_rn(w5, VR);
    float wv7 = __fmul_rn(w7, VR);

    float b3     = __fmul_rn(w9, VREF);    // j=3 threshold (bit-independent)
    float b2base = __fmul_rn(w8, VREF);
    float b1base = __fmul_rn(w6, VREF);
    float b0base = __fmul_rn(w3, VREF);

    const bool in = (4 * t4 < n);          // n % 4 == 0 (12M), whole-vector guard
    float4 xv = make_float4(0.f, 0.f, 0.f, 0.f);
    if (in) xv = x4[t4];                   // 16 B/lane, lane-contiguous

    const float bw0 = 0.1125f, bw1 = 0.225f, bw2 = 0.45f, bw3 = 0.9f;

    float xe[4] = {xv.x, xv.y, xv.z, xv.w};
    float qe[4];

    #pragma unroll
    for (int j = 0; j < 4; ++j) {
        float xj = xe[j];

        bool s3 = (xj >= b3);

        float b2 = b2base;
        if (s3) b2 = __fadd_rn(b2, wv7);
        bool s2 = (xj >= b2);

        float b1 = b1base;                 // k=2 then k=3 (reference order)
        if (s2) b1 = __fadd_rn(b1, wv5);
        if (s3) b1 = __fadd_rn(b1, wv4);
        bool s1 = (xj >= b1);

        float b0 = b0base;                 // k=1,2,3 in reference order
        if (s1) b0 = __fadd_rn(b0, wv2);
        if (s2) b0 = __fadd_rn(b0, wv1);
        if (s3) b0 = __fadd_rn(b0, wv0);
        bool s0 = (xj >= b0);

        float qv = s0 ? bw0 : 0.0f;
        if (s1) qv = __fadd_rn(qv, bw1);
        if (s2) qv = __fadd_rn(qv, bw2);
        if (s3) qv = __fadd_rn(qv, bw3);
        qe[j] = qv;

        // Stage this element's Q vector into swizzled LDS slot.
        float4 Qv;
        Qv.x = s0 ? 1.0f : -1.0f;
        Qv.y = s1 ? 1.0f : -1.0f;
        Qv.z = s2 ? 1.0f : -1.0f;
        Qv.w = s3 ? 1.0f : -1.0f;
        int s = 4 * tid + j;
        lds[s ^ ((s >> 4) & 3)] = Qv;      // ds_write_b128, 2-way (free)
    }

    if (in) q4[t4] = make_float4(qe[0], qe[1], qe[2], qe[3]);   // 16 B/lane

    __syncthreads();

    // Cooperative lane-contiguous Q writeout: 4 passes x 4 KB/wave-instr.
    #pragma unroll
    for (int p = 0; p < 4; ++p) {
        int s = tid + 256 * p;
        float4 v = lds[s ^ ((s >> 4) & 3)];   // ds_read_b128, conflict-free
        int g = e0 + s;                       // global element == float4 index in Q
        if (g < n) Q4[g] = v;
    }
}

extern "C" void kernel_launch(void* const* d_in, const int* in_sizes, int n_in,
                              void* d_out, int out_size, void* d_ws, size_t ws_size,
                              hipStream_t stream)
{
    const float* x = (const float*)d_in[0];   // [500000, 24] f32
    const float* W = (const float*)d_in[1];   // [10] f32
    int n = in_sizes[0];                      // 12,000,000 (divisible by 4)

    float* q  = (float*)d_out;                // [n] f32
    float4* Q = (float4*)((float*)d_out + n); // [n, 4] f32

    const int block = 256;
    const int per_block = 1024;               // 4 elements/thread
    const int grid = (n + per_block - 1) / per_block;
    sar_adc_kernel<<<grid, block, 0, stream>>>(
        (const float4*)x, W, (float4*)q, Q, n);
}

// Round 6
// 266.343 us; speedup vs baseline: 1.0199x; 1.0199x over previous
//
#include <hip/hip_runtime.h>

// SAR-ADC 4-bit successive-approximation quantizer.
// Element-wise over N = LENGTH*NADC = 12M floats. Memory-bound:
//   read x (48 MB), write q (48 MB) + Q (192 MB); kernel floor ~44-46 us.
//
// v5b = round-1 structure (empirically fastest: 1 elem/thread, max TLP,
// minimal per-thread work; measured ~55 us vs ~61-62 for 4-elem variants)
// + nontemporal hints. NT is safe here because every store instruction
// covers whole 128-B lines (Q: 16B x 64 lanes = 8 full lines/instr;
// q: dword x 64 lanes = 2 full lines/instr) — unlike v2, whose 64-B-lane-
// stride NT stores left partial lines and doubled WRITE_SIZE.
// (v5 failed to compile: __builtin_nontemporal_store needs a clang
// ext_vector_type pointer, not HIP's float4 struct. Using v4f here.)
//
// Numerics: reference does float32 ops throughout. (Q+1)*0.5 is exactly
// 0.0 or 1.0, so each bit_sum = fl(W[m]*VREF) + subset of fl(W[k]*VR),
// added in the reference's fixed order. __fmul_rn/__fadd_rn prevent FMA
// contraction -> bit-exact thresholds -> bit-exact sign decisions.
// sign(x - b + 1e-30) == (x >= b ? +1 : -1): nonzero diffs are >= ~1e-9,
// DELTA only rescues diff==0.  (absmax has measured 0.0 every round.)

typedef float v4f __attribute__((ext_vector_type(4)));

__global__ __launch_bounds__(256)
void sar_adc_kernel(const float* __restrict__ x, const float* __restrict__ W,
                    float* __restrict__ q_out, v4f* __restrict__ Q4, int n)
{
    int e = blockIdx.x * blockDim.x + threadIdx.x;
    if (e >= n) return;

    const float VREF = 0.1125f;   // fl32(1.8/16)
    const float VR   = 0.1125f;

    // Wave-uniform W loads (compiler lifts to s_load).
    float w0 = W[0], w1 = W[1], w2 = W[2], w3 = W[3], w4 = W[4];
    float w5 = W[5], w6 = W[6], w7 = W[7], w8 = W[8], w9 = W[9];

    // fl(W[k]*VR) terms (exactly the reference's contribution when bit set)
    float wv0 = __fmul_rn(w0, VR);
    float wv1 = __fmul_rn(w1, VR);
    float wv2 = __fmul_rn(w2, VR);
    float wv4 = __fmul_rn(w4, VR);
    float wv5 = __fmul_rn(w5, VR);
    float wv7 = __fmul_rn(w7, VR);

    float xv = __builtin_nontemporal_load(&x[e]);

    // j = 3: bit_sum = W[9]*VREF
    float b3 = __fmul_rn(w9, VREF);
    bool s3 = (xv >= b3);

    // j = 2: W[8]*VREF + (Q3+1)*0.5*W[7]*VR
    float b2 = __fmul_rn(w8, VREF);
    if (s3) b2 = __fadd_rn(b2, wv7);
    bool s2 = (xv >= b2);

    // j = 1: W[6]*VREF + (Q2..)*W[5]*VR + (Q3..)*W[4]*VR   (k=2 then k=3)
    float b1 = __fmul_rn(w6, VREF);
    if (s2) b1 = __fadd_rn(b1, wv5);
    if (s3) b1 = __fadd_rn(b1, wv4);
    bool s1 = (xv >= b1);

    // j = 0: W[3]*VREF + (Q1..)*W[2]*VR + (Q2..)*W[1]*VR + (Q3..)*W[0]*VR
    float b0 = __fmul_rn(w3, VREF);
    if (s1) b0 = __fadd_rn(b0, wv2);
    if (s2) b0 = __fadd_rn(b0, wv1);
    if (s3) b0 = __fadd_rn(b0, wv0);
    bool s0 = (xv >= b0);

    // q = sum_k (Q_k+1)*0.5 * bw_k, bw_k = fl32(0.1125)*2^k (exact scalings)
    const float bw0 = 0.1125f, bw1 = 0.225f, bw2 = 0.45f, bw3 = 0.9f;
    float qv = s0 ? bw0 : 0.0f;
    if (s1) qv = __fadd_rn(qv, bw1);
    if (s2) qv = __fadd_rn(qv, bw2);
    if (s3) qv = __fadd_rn(qv, bw3);

    __builtin_nontemporal_store(qv, &q_out[e]);

    // Q[e] is 4 contiguous floats -> one 16B store, lane-contiguous
    // (4 KB/wave-instr = 8 complete 128-B lines per instruction).
    v4f Qv;
    Qv.x = s0 ? 1.0f : -1.0f;
    Qv.y = s1 ? 1.0f : -1.0f;
    Qv.z = s2 ? 1.0f : -1.0f;
    Qv.w = s3 ? 1.0f : -1.0f;
    __builtin_nontemporal_store(Qv, &Q4[e]);
}

extern "C" void kernel_launch(void* const* d_in, const int* in_sizes, int n_in,
                              void* d_out, int out_size, void* d_ws, size_t ws_size,
                              hipStream_t stream)
{
    const float* x = (const float*)d_in[0];   // [500000, 24] f32
    const float* W = (const float*)d_in[1];   // [10] f32
    int n = in_sizes[0];                      // 12,000,000

    float* q = (float*)d_out;                 // [n] f32
    v4f* Q   = (v4f*)((float*)d_out + n);     // [n, 4] f32

    const int block = 256;
    const int grid = (n + block - 1) / block;
    sar_adc_kernel<<<grid, block, 0, stream>>>(x, W, q, Q, n);
}